// Round 9
// baseline (167.539 us; speedup 1.0000x reference)
//
#include <hip/hip_runtime.h>
#include <math.h>

#define NPIX 65536
#define NB   4
#define NK   6
#define TK   8
#define NBUK 48   // NK*TK
#define NCH  256
#define GB   128  // pixel chunks (512 px) per batch in k_gemm
#define CHSP 2    // channel halves per batch in k_gemm
#define NSEL (NB*NK*TK)     // 192 selections
#define CCAP 65536

typedef __attribute__((ext_vector_type(8))) short bf16x8;
typedef __attribute__((ext_vector_type(4))) float f32x4;

// ---------------- init: zero atomic targets ----------------
__global__ __launch_bounds__(64) void k_init(unsigned* m_arr, unsigned* Mbits) {
  int t = threadIdx.x;
  if (t < NB * NK) { m_arr[t] = 0u; Mbits[t] = 0u; }
}

// ---------------- A1: cert, argmax, per-class m/M, ballot-based compaction ----------------
__global__ __launch_bounds__(256) void k_cert(const float* __restrict__ preds,
    float* __restrict__ cert, unsigned char* __restrict__ argm,
    unsigned* __restrict__ m_arr, unsigned* __restrict__ Mbits,
    float* __restrict__ clist) {
  __shared__ unsigned s_max[NK];
  __shared__ unsigned s_seg[4][4][NK];
  __shared__ unsigned s_segbase[4][4][NK];
  __shared__ unsigned s_bbase[NK];
  int tid = threadIdx.x;
  int w = tid >> 6, lane = tid & 63;
  if (tid < NK) s_max[tid] = 0u;
  __syncthreads();
  int i = blockIdx.x * 256 + tid;
  int n4 = i << 2;
  int b = n4 >> 16;
  int n = n4 & (NPIX - 1);
  const float* pb = preds + (size_t)b * NK * NPIX + n;
  float4 pv[NK];
  #pragma unroll
  for (int k = 0; k < NK; ++k) pv[k] = *(const float4*)(pb + (size_t)k * NPIX);
  float cv[4]; int cls[4]; unsigned av = 0;
  #pragma unroll
  for (int j = 0; j < 4; ++j) {
    float m1 = -INFINITY, m2 = -INFINITY; int arg = 0;
    #pragma unroll
    for (int k = 0; k < NK; ++k) {
      float v = (j == 0) ? pv[k].x : (j == 1) ? pv[k].y : (j == 2) ? pv[k].z : pv[k].w;
      if (v > m1) { m2 = m1; m1 = v; arg = k; }
      else if (v > m2) m2 = v;
    }
    cv[j] = m1 - m2;                        // >= 0
    cls[j] = arg;
    av |= ((unsigned)arg) << (8 * j);
    atomicMax(&s_max[arg], __float_as_uint(cv[j]));
  }
  *(float4*)(cert + (size_t)b * NPIX + n) = make_float4(cv[0], cv[1], cv[2], cv[3]);
  *(unsigned*)(argm + (size_t)b * NPIX + n) = av;
  unsigned long long lmask = ((unsigned long long)1 << lane) - 1ull;
  unsigned myoff[4];
  #pragma unroll
  for (int j = 0; j < 4; ++j) {
    #pragma unroll
    for (int c = 0; c < NK; ++c) {
      unsigned long long mk = __ballot(cls[j] == c);
      if (cls[j] == c) myoff[j] = (unsigned)__popcll(mk & lmask);
      if (lane == 0) s_seg[w][j][c] = (unsigned)__popcll(mk);
    }
  }
  __syncthreads();
  if (tid < NK) {
    unsigned run = 0;
    #pragma unroll
    for (int s = 0; s < 16; ++s) {
      unsigned v = s_seg[s >> 2][s & 3][tid];
      s_segbase[s >> 2][s & 3][tid] = run;
      run += v;
    }
    s_bbase[tid] = atomicAdd(&m_arr[b * NK + tid], run);
    atomicMax(&Mbits[b * NK + tid], s_max[tid]);
  }
  __syncthreads();
  #pragma unroll
  for (int j = 0; j < 4; ++j) {
    int c = cls[j];
    clist[(size_t)(b * NK + c) * CCAP + s_bbase[c] + s_segbase[w][j][c] + myoff[j]] = cv[j];
  }
}

// ---------------- A2: one block per (b,c,t); 4 radix passes over compacted list ----------
__global__ __launch_bounds__(256) void k_thresh(const float* __restrict__ clist,
    const unsigned* __restrict__ m_arr, float* __restrict__ thr) {
  int g = blockIdx.x;
  int bc = g >> 3;
  int t = g & 7;
  int tid = threadIdx.x;
  __shared__ unsigned hist[256];
  __shared__ unsigned s_sel, s_rank;
  unsigned m = m_arr[bc];
  if (m == 0) { if (tid == 0) thr[g] = 0.f; return; }
  unsigned long long ks = ((unsigned long long)m * (unsigned)(t + 1)) / TK;
  unsigned rank = ks ? (unsigned)ks : 1u;
  const unsigned* lp = (const unsigned*)clist + (size_t)bc * CCAP;
  unsigned prefix = 0;
  for (int pass = 0; pass < 4; ++pass) {
    int shift = 24 - 8 * pass;
    hist[tid] = 0u;
    __syncthreads();
    for (unsigned idx = tid; idx < m; idx += 256) {
      unsigned u = lp[idx];
      if (pass == 0 || (u >> (shift + 8)) == prefix)
        atomicAdd(&hist[(u >> shift) & 255u], 1u);
    }
    __syncthreads();
    if (tid == 0) {
      unsigned cum = 0, rn = rank, sel = 0;
      for (int bin = 255; bin >= 0; --bin) {
        unsigned hh = hist[bin]; cum += hh;
        if (cum >= rank) { sel = (unsigned)bin; rn = rank - (cum - hh); break; }
      }
      s_sel = sel; s_rank = rn;
    }
    __syncthreads();
    prefix = (prefix << 8) | s_sel;
    rank = s_rank;
    __syncthreads();
  }
  if (tid == 0) thr[g] = __uint_as_float(prefix);
}

// ---------------- A3: packed (e | bucket) + deterministic Z partials ----------------
__global__ __launch_bounds__(256) void k_bucket(const float* __restrict__ cert,
    const unsigned char* __restrict__ argm, const unsigned* __restrict__ Mbits,
    const float* __restrict__ thr, unsigned* __restrict__ eb_out,
    float* __restrict__ zpart) {
  __shared__ float zacc[4 * NBUK * 64];
  __shared__ float wpart[4 * NBUK];
  __shared__ float s_thr[NSEL];
  __shared__ float s_M[NB * NK];
  int tid = threadIdx.x;
  int w = tid >> 6, lane = tid & 63;
  float* mycol = zacc + (size_t)w * NBUK * 64 + lane;
  if (tid < NSEL) s_thr[tid] = thr[tid];
  if (tid < NB * NK) s_M[tid] = __uint_as_float(Mbits[tid]);
  #pragma unroll
  for (int k = 0; k < NBUK; ++k) mycol[k * 64] = 0.f;
  __syncthreads();
  int i = blockIdx.x * 256 + tid;
  int n4 = i << 2;
  int b = n4 >> 16;
  int n = n4 & (NPIX - 1);
  float4 cv = *(const float4*)(cert + (size_t)b * NPIX + n);
  unsigned av = *(const unsigned*)(argm + (size_t)b * NPIX + n);
  unsigned evv[4];
  #pragma unroll
  for (int j = 0; j < 4; ++j) {
    int c = (av >> (8 * j)) & 255;
    float ce = (j == 0) ? cv.x : (j == 1) ? cv.y : (j == 2) ? cv.z : cv.w;
    float e = expf(ce - s_M[b * NK + c]);
    const float* tc = &s_thr[(b * NK + c) * TK];
    int tmin = TK - 1;
    #pragma unroll
    for (int tt = TK - 2; tt >= 0; --tt) if (ce >= tc[tt]) tmin = tt;
    evv[j] = (__float_as_uint(e) & 0xFFFFFFC0u) | (unsigned)(c * TK + tmin);
    // Z from the SAME bf16-truncated e that k_gemm uses -> rounding cancels in P/Z
    mycol[(evv[j] & 63u) * 64] += __uint_as_float(evv[j] & 0xFFFF0000u);
  }
  uint4 ev; ev.x = evv[0]; ev.y = evv[1]; ev.z = evv[2]; ev.w = evv[3];
  *(uint4*)(eb_out + (size_t)b * NPIX + n) = ev;
  __syncthreads();
  for (int k = 0; k < NBUK; ++k) {
    float v = mycol[k * 64];
    #pragma unroll
    for (int d = 1; d < 64; d <<= 1) v += __shfl_xor(v, d, 64);
    if (lane == 0) wpart[w * NBUK + k] = v;
  }
  __syncthreads();
  if (tid < NBUK)
    zpart[(size_t)blockIdx.x * NBUK + tid] =
      wpart[tid] + wpart[NBUK + tid] + wpart[2 * NBUK + tid] + wpart[3 * NBUK + tid];
}

// ---------------- Zred: 64 block-partials per batch -> zfin[b][48] ----------------
__global__ __launch_bounds__(192) void k_zred(const float* __restrict__ zpart,
                                              float* __restrict__ zfin) {
  int t = threadIdx.x;
  int b = t / NBUK, k = t % NBUK;
  float s = 0.f;
  for (int i = 0; i < 64; ++i) s += zpart[(size_t)(b * 64 + i) * NBUK + k];
  zfin[b * NBUK + k] = s;
}

// ---------------- B: MFMA GEMM, occupancy-tuned ----------
// grid = NB*CHSP*GB = 1024 blocks, 512 thr; block = (b, chh:128ch, g:512px).
// psum layout [g][b*NCH+ch][48]; epilogue staged through LDS for contiguous stores.
__global__ __launch_bounds__(512) void k_gemm(const float* __restrict__ x,
    const unsigned* __restrict__ eb, float* __restrict__ psum) {
  __shared__ char smem[49152];              // E (48KB bf16) then reused as Ct f32[128][52]
  short* E = (short*)smem;
  int tid = threadIdx.x;
  int w = tid >> 6, lane = tid & 63;
  int bid = blockIdx.x;
  int g = bid & (GB - 1);
  int chh = (bid >> 7) & (CHSP - 1);
  int b = bid >> 8;
  const unsigned* ebp = eb + (size_t)b * NPIX + g * 512;
  const float* xb = x + ((size_t)b * NCH + chh * 128) * NPIX;
  int chl = w * 16 + (lane & 15);           // local channel 0..127
  f32x4 acc[3];
  #pragma unroll
  for (int m = 0; m < 3; ++m) acc[m] = (f32x4){0.f, 0.f, 0.f, 0.f};
  #pragma unroll
  for (int z = 0; z < 6; ++z)
    ((uint4*)E)[z * 512 + tid] = (uint4){0u, 0u, 0u, 0u};
  __syncthreads();
  {                                          // scatter 512 pixels, collision-free
    unsigned u = ebp[tid];
    unsigned bk = u & 63u;
    int ks = tid >> 5, k = tid & 31;
    int el = (int)(bk & 15u) + ((k >> 3) << 4);
    E[((ks * 3 + (int)(bk >> 4)) * 64 + el) * 8 + (k & 7)] = (short)(u >> 16);
  }
  __syncthreads();
  int nbase = g * 512;
  const float* xrow = xb + (size_t)chl * NPIX + nbase + ((lane >> 4) << 3);
  #pragma unroll 2
  for (int ks = 0; ks < 16; ++ks) {
    bf16x8 A0 = ((bf16x8*)E)[(ks * 3 + 0) * 64 + lane];
    bf16x8 A1 = ((bf16x8*)E)[(ks * 3 + 1) * 64 + lane];
    bf16x8 A2 = ((bf16x8*)E)[(ks * 3 + 2) * 64 + lane];
    const float* xp = xrow + ks * 32;
    float4 xa = *(const float4*)xp;
    float4 xc = *(const float4*)(xp + 4);
    float xv[8] = {xa.x, xa.y, xa.z, xa.w, xc.x, xc.y, xc.z, xc.w};
    bf16x8 Bh, Bl;
    #pragma unroll
    for (int j = 0; j < 8; ++j) {
      unsigned u = __float_as_uint(xv[j]);
      float hf = __uint_as_float(u & 0xFFFF0000u);   // truncated-bf16 hi
      float lo = xv[j] - hf;                          // exact residual
      Bh[j] = (short)(u >> 16);
      Bl[j] = (short)(__float_as_uint(lo) >> 16);
    }
    acc[0] = __builtin_amdgcn_mfma_f32_16x16x32_bf16(A0, Bh, acc[0], 0, 0, 0);
    acc[1] = __builtin_amdgcn_mfma_f32_16x16x32_bf16(A1, Bh, acc[1], 0, 0, 0);
    acc[2] = __builtin_amdgcn_mfma_f32_16x16x32_bf16(A2, Bh, acc[2], 0, 0, 0);
    acc[0] = __builtin_amdgcn_mfma_f32_16x16x32_bf16(A0, Bl, acc[0], 0, 0, 0);
    acc[1] = __builtin_amdgcn_mfma_f32_16x16x32_bf16(A1, Bl, acc[1], 0, 0, 0);
    acc[2] = __builtin_amdgcn_mfma_f32_16x16x32_bf16(A2, Bl, acc[2], 0, 0, 0);
  }
  // epilogue: C layout col=lane&15 (ch), row=(lane>>4)*4+i (bucket) [m89-verified]
  __syncthreads();
  float* Ct = (float*)smem;                 // [128][52] padded
  #pragma unroll
  for (int m = 0; m < 3; ++m)
    #pragma unroll
    for (int i = 0; i < 4; ++i)
      Ct[chl * 52 + m * 16 + ((lane >> 4) << 2) + i] = acc[m][i];
  __syncthreads();
  float* dst = psum + ((size_t)g * NB * NCH + (size_t)b * NCH + chh * 128) * NBUK;
  int r = tid >> 2, p = tid & 3;            // 4 threads/row, 12 floats each
  #pragma unroll
  for (int j = 0; j < 3; ++j) {
    float4 v = *(const float4*)(Ct + r * 52 + p * 12 + j * 4);
    *(float4*)(dst + r * NBUK + p * 12 + j * 4) = v;
  }
}

// ---------------- F: reduce 128 g-partials, prefix over t, write fs+fg -------
__global__ __launch_bounds__(64) void k_final(const float* __restrict__ psum,
    const float* __restrict__ zfin, const unsigned* __restrict__ m_arr,
    float* __restrict__ out) {
  int bc_ = blockIdx.x;                     // (b*NCH + ch), 1024 blocks
  int lane = threadIdx.x;
  int b = bc_ >> 8;
  float p48[NBUK];
  #pragma unroll
  for (int k = 0; k < NBUK; ++k) p48[k] = 0.f;
  #pragma unroll
  for (int gg = 0; gg < GB / 64; ++gg) {
    const float* ps = psum + ((size_t)(gg * 64 + lane) * NB * NCH + bc_) * NBUK;
    #pragma unroll
    for (int i = 0; i < 12; ++i) {
      float4 v = ((const float4*)ps)[i];
      p48[4 * i] += v.x; p48[4 * i + 1] += v.y; p48[4 * i + 2] += v.z; p48[4 * i + 3] += v.w;
    }
  }
  #pragma unroll
  for (int d = 1; d < 64; d <<= 1)
    #pragma unroll
    for (int k = 0; k < NBUK; ++k) p48[k] += __shfl_xor(p48[k], d, 64);
  if (lane == 0) {
    float* fs = out + (size_t)bc_ * NBUK;
    float* fg = out + (size_t)NB * NCH * NBUK + (size_t)bc_ * NK;
    float t5[TK];
    #pragma unroll
    for (int c = 0; c < NK; ++c) {
      unsigned m = m_arr[b * NK + c];
      float P = 0.f, Z = 0.f;
      float vals[TK];
      #pragma unroll
      for (int t = 0; t < TK; ++t) {
        P += p48[c * TK + t];
        Z += zfin[b * NBUK + c * TK + t];
        vals[t] = P / Z;
      }
      float tot = vals[TK - 1];
      #pragma unroll
      for (int t = 0; t < TK; ++t) {
        float v = (m == 0u) ? 0.f : ((m < (unsigned)TK) ? tot : vals[t]);
        fs[c * TK + t] = v;
        if (c == NK - 1) t5[t] = v;
      }
    }
    #pragma unroll
    for (int v = 0; v < NK; ++v) fg[v] = t5[2 + v];
  }
}

extern "C" void kernel_launch(void* const* d_in, const int* in_sizes, int n_in,
                              void* d_out, int out_size, void* d_ws, size_t ws_size,
                              hipStream_t stream) {
  const float* x     = (const float*)d_in[0];   // [4,256,256,256]
  const float* preds = (const float*)d_in[1];   // [4,6,256,256]
  float* out = (float*)d_out;
  char* ws = (char*)d_ws;
  float*         cert  = (float*)(ws);                       // 1 MiB
  unsigned char* argm  = (unsigned char*)(ws + 0x100000);    // 256 KiB
  unsigned*      eb    = (unsigned*)(ws + 0x140000);         // 1 MiB
  float*         clist = (float*)(ws + 0x240000);            // 6 MiB (union w/ psum)
  float*         psum  = (float*)(ws + 0x240000);            // 24 MiB (after k_thresh)
  unsigned*      m_arr = (unsigned*)(ws + 0x1A80000);        // 24 u32
  unsigned*      Mbits = (unsigned*)(ws + 0x1A80100);        // 24 u32
  float*         thr   = (float*)(ws + 0x1A80200);           // 192 f32
  float*         zpart = (float*)(ws + 0x1A81000);           // 48 KiB
  float*         zfin  = (float*)(ws + 0x1A8E000);           // 768 B

  k_init  <<<1, 64, 0, stream>>>(m_arr, Mbits);
  k_cert  <<<256, 256, 0, stream>>>(preds, cert, argm, m_arr, Mbits, clist);
  k_thresh<<<NSEL, 256, 0, stream>>>(clist, m_arr, thr);
  k_bucket<<<256, 256, 0, stream>>>(cert, argm, Mbits, thr, eb, zpart);
  k_zred  <<<1, 192, 0, stream>>>(zpart, zfin);
  k_gemm  <<<NB * CHSP * GB, 512, 0, stream>>>(x, eb, psum);
  k_final <<<NB * NCH, 64, 0, stream>>>(psum, zfin, m_arr, out);
}